// Round 1
// baseline (1572.479 us; speedup 1.0000x reference)
//
#include <hip/hip_runtime.h>
#include <math.h>

#define BB 2
#define LL 2048
#define DM 768
#define DS 16
#define NTOK (BB*LL)

__device__ __forceinline__ float sigf(float x){ return 1.f/(1.f+__expf(-x)); }

// ---------------- LayerNorm: one block per token ----------------
__global__ __launch_bounds__(256) void ln_kernel(const float* __restrict__ x,
                                                 const float* __restrict__ w,
                                                 const float* __restrict__ b,
                                                 float* __restrict__ xn){
  __shared__ float red[8];
  int tok = blockIdx.x, tid = threadIdx.x;
  const float* xr = x + (size_t)tok*DM;
  float a0 = xr[tid], a1 = xr[tid+256], a2 = xr[tid+512];
  float s = a0+a1+a2;
  float q = a0*a0 + a1*a1 + a2*a2;
  #pragma unroll
  for (int o=32;o>=1;o>>=1){ s += __shfl_xor(s,o); q += __shfl_xor(q,o); }
  int wid = tid>>6;
  if ((tid&63)==0){ red[wid]=s; red[4+wid]=q; }
  __syncthreads();
  if (tid==0){
    float S = red[0]+red[1]+red[2]+red[3];
    float Q = red[4]+red[5]+red[6]+red[7];
    float mu = S*(1.f/768.f);
    float var = Q*(1.f/768.f) - mu*mu;
    red[0]=mu; red[1]=rsqrtf(var+1e-5f);
  }
  __syncthreads();
  float mu = red[0], r = red[1];
  float* o = xn + (size_t)tok*DM;
  o[tid]     = (a0-mu)*r*w[tid]     + b[tid];
  o[tid+256] = (a1-mu)*r*w[tid+256] + b[tid+256];
  o[tid+512] = (a2-mu)*r*w[tid+512] + b[tid+512];
}

// ---------------- Tiled fp32 GEMM: C[M,N] = A[M,K] @ W[N,K]^T + bias ----------------
// MODE 0: in_proj. col<768 -> out0 (x_ssm), col>=768 -> out1 = silu(v) (gate)
// MODE 1: out_proj. A-prologue: a = A*A2 (y * silu_gate). out0 = v + resid.
template<int MODE>
__global__ __launch_bounds__(256) void gemm_kernel(const float* __restrict__ A,
                                                   const float* __restrict__ A2,
                                                   const float* __restrict__ W,
                                                   const float* __restrict__ bias,
                                                   const float* __restrict__ resid,
                                                   float* __restrict__ out0,
                                                   float* __restrict__ out1,
                                                   int M, int N, int K){
  __shared__ float As[64][17];
  __shared__ float Bs[64][17];
  int tid = threadIdx.x;
  int m0 = blockIdx.y*64, n0 = blockIdx.x*64;
  int lr = tid>>2;         // 0..63
  int lk = (tid&3)*4;      // 0,4,8,12
  int ty = tid>>4, tx = tid&15;
  float acc[4][4] = {};
  for (int k0=0; k0<K; k0+=16){
    float4 a4 = *(const float4*)(A + (size_t)(m0+lr)*K + k0 + lk);
    if (MODE==1){
      float4 g4 = *(const float4*)(A2 + (size_t)(m0+lr)*K + k0 + lk);
      a4.x*=g4.x; a4.y*=g4.y; a4.z*=g4.z; a4.w*=g4.w;
    }
    float4 b4 = *(const float4*)(W + (size_t)(n0+lr)*K + k0 + lk);
    As[lr][lk]=a4.x; As[lr][lk+1]=a4.y; As[lr][lk+2]=a4.z; As[lr][lk+3]=a4.w;
    Bs[lr][lk]=b4.x; Bs[lr][lk+1]=b4.y; Bs[lr][lk+2]=b4.z; Bs[lr][lk+3]=b4.w;
    __syncthreads();
    #pragma unroll
    for (int kk=0; kk<16; kk++){
      float a[4], bb[4];
      #pragma unroll
      for (int i=0;i<4;i++) a[i]  = As[ty*4+i][kk];
      #pragma unroll
      for (int j=0;j<4;j++) bb[j] = Bs[tx*4+j][kk];
      #pragma unroll
      for (int i=0;i<4;i++)
        #pragma unroll
        for (int j=0;j<4;j++)
          acc[i][j] = fmaf(a[i], bb[j], acc[i][j]);
    }
    __syncthreads();
  }
  #pragma unroll
  for (int i=0;i<4;i++){
    int row = m0 + ty*4 + i;
    #pragma unroll
    for (int j=0;j<4;j++){
      int col = n0 + tx*4 + j;
      float v = acc[i][j] + bias[col];
      if (MODE==0){
        if (col < DM) out0[(size_t)row*DM + col] = v;
        else          out1[(size_t)row*DM + (col-DM)] = v/(1.f+__expf(-v));
      } else {
        out0[(size_t)row*DM + col] = v + resid[(size_t)row*DM + col];
      }
    }
  }
}

// ---------------- causal depthwise conv (k=4) + SiLU ----------------
__global__ __launch_bounds__(256) void conv_silu_kernel(const float* __restrict__ xs,
                                                        const float* __restrict__ cw,
                                                        const float* __restrict__ cb,
                                                        float* __restrict__ xc){
  int idx = blockIdx.x*256 + threadIdx.x;
  if (idx >= NTOK*DM) return;
  int d = idx % DM;
  int l = (idx / DM) % LL;
  float acc = cb[d] + cw[d*4+3]*xs[idx];
  if (l>=1) acc = fmaf(cw[d*4+2], xs[idx-DM],   acc);
  if (l>=2) acc = fmaf(cw[d*4+1], xs[idx-2*DM], acc);
  if (l>=3) acc = fmaf(cw[d*4+0], xs[idx-3*DM], acc);
  xc[idx] = acc/(1.f+__expf(-acc));
}

// ---------------- transpose x_proj_w [32,768] -> [768,32] ----------------
__global__ __launch_bounds__(256) void transpose_w(const float* __restrict__ w,
                                                   float* __restrict__ wt){
  int idx = blockIdx.x*256 + threadIdx.x;
  if (idx >= 32*768) return;
  int n = idx/768, k = idx%768;
  wt[k*32+n] = w[idx];
}

// ---------------- x_proj: BC[NTOK,32] = xc @ wt + b ----------------
__global__ __launch_bounds__(256) void xproj_kernel(const float* __restrict__ xc,
                                                    const float* __restrict__ wt,
                                                    const float* __restrict__ bias,
                                                    float* __restrict__ BC){
  int tid = threadIdx.x;
  int n = tid & 31, tloc = tid >> 5;
  int m = blockIdx.x*8 + tloc;
  const float* xr = xc + (size_t)m*DM;
  float a0=0,a1=0,a2=0,a3=0;
  #pragma unroll 4
  for (int k=0;k<DM;k+=4){
    a0 = fmaf(xr[k],   wt[(k)*32+n],   a0);
    a1 = fmaf(xr[k+1], wt[(k+1)*32+n], a1);
    a2 = fmaf(xr[k+2], wt[(k+2)*32+n], a2);
    a3 = fmaf(xr[k+3], wt[(k+3)*32+n], a3);
  }
  BC[(size_t)m*32+n] = (a0+a1)+(a2+a3) + bias[n];
}

// ---------------- sequential gated scan ----------------
// 96 blocks x 64 threads. block -> (b, 16-channel chunk). thread -> (channel, 4 states)
__global__ __launch_bounds__(64) void scan_kernel(const float* __restrict__ xconv,
                                                  const float* __restrict__ BC,
                                                  const float* __restrict__ opp,
                                                  const float* __restrict__ A_log,
                                                  const float* __restrict__ Dp_,
                                                  const float* __restrict__ gl,
                                                  const float* __restrict__ ctgt,
                                                  float* __restrict__ y,
                                                  float* __restrict__ states){
  int bid = blockIdx.x;
  int b = bid/48, chunk = bid%48;
  int lane = threadIdx.x;
  int c = lane & 15, g = lane >> 4;
  int d = chunk*16 + c;
  float A_[4], ct_[4];
  #pragma unroll
  for (int j=0;j<4;j++){
    A_[j] = expf(-expf(A_log[d*DS + g*4 + j]));
    ct_[j] = ctgt[g*4+j];
  }
  float Dp = Dp_[d];
  float gs2 = sigf(gl[2]), gs4 = sigf(gl[4]), gs5 = sigf(gl[5]);
  float h[4] = {0,0,0,0}, ck[4] = {0,0,0,0};
  const size_t base = (size_t)b*LL;
  for (int t=0; t<LL; t++){
    size_t tok = base + t;
    float xc = xconv[tok*DM + d];
    const float* op = opp + tok*6;
    float iw = op[2]*gs2, pcs = op[3], cw = op[4]*gs4, zw = op[5]*gs5;
    const float* bc = BC + tok*32;
    float yp = 0.f;
    float v[4];
    #pragma unroll
    for (int j=0;j<4;j++){
      float Bt = bc[g*4+j], Ct = bc[16+g*4+j];
      float hold = h[j];
      float hn  = fmaf(A_[j], hold, xc*Bt);
      float ckn = fmaf(pcs, hold - ck[j], ck[j]);
      hn = fmaf(iw, hold - hn, hn);
      hn = fmaf(cw, ckn  - hn, hn);
      hn = fmaf(zw, ct_[j] - hn, hn);
      yp = fmaf(Ct, hn, yp);
      h[j] = hn; ck[j] = ckn; v[j] = hn;
    }
    yp += __shfl_xor(yp, 16);
    yp += __shfl_xor(yp, 32);
    if (g==0) y[tok*DM + d] = fmaf(Dp, xc, yp);
    // shrinking butterfly over the 16 channel-lanes of this sgroup
    float t0=__shfl_xor(v[0],1), t1=__shfl_xor(v[1],1), t2=__shfl_xor(v[2],1), t3=__shfl_xor(v[3],1);
    float w0, w1;
    if (lane & 1){ w0 = v[2]+t2; w1 = v[3]+t3; }
    else         { w0 = v[0]+t0; w1 = v[1]+t1; }
    float u0=__shfl_xor(w0,2), u1=__shfl_xor(w1,2);
    float z = (lane & 2) ? (w1+u1) : (w0+u0);
    z += __shfl_xor(z,4);
    z += __shfl_xor(z,8);
    if ((lane & 12) == 0){
      int s_local = ((lane&1)<<1) | ((lane>>1)&1);
      atomicAdd(states + tok*DS + g*4 + s_local, z*(1.f/768.f));
    }
  }
}

extern "C" void kernel_launch(void* const* d_in, const int* in_sizes, int n_in,
                              void* d_out, int out_size, void* d_ws, size_t ws_size,
                              hipStream_t stream){
  const float* x        = (const float*)d_in[0];
  const float* op_probs = (const float*)d_in[1];
  const float* norm_w   = (const float*)d_in[2];
  const float* norm_b   = (const float*)d_in[3];
  const float* in_w     = (const float*)d_in[4];
  const float* in_b     = (const float*)d_in[5];
  const float* conv_w   = (const float*)d_in[6];
  const float* conv_b   = (const float*)d_in[7];
  const float* xp_w     = (const float*)d_in[8];
  const float* xp_b     = (const float*)d_in[9];
  const float* out_w    = (const float*)d_in[10];
  const float* out_b    = (const float*)d_in[11];
  const float* A_log    = (const float*)d_in[12];
  const float* D_param  = (const float*)d_in[13];
  const float* gate_l   = (const float*)d_in[14];
  const float* coll_t   = (const float*)d_in[15];

  float* out0 = (float*)d_out;
  float* out1 = out0 + (size_t)NTOK*DM;

  float* ws    = (float*)d_ws;
  const size_t SZ = (size_t)NTOK*DM;       // 3145728
  float* xn_y  = ws;            // xn, later reused for scan y
  float* xssm  = ws + SZ;
  float* sgate = ws + 2*SZ;
  float* xconv = ws + 3*SZ;
  float* BC    = ws + 4*SZ;     // NTOK*32
  float* wt    = BC + (size_t)NTOK*32;  // 768*32

  hipMemsetAsync(out1, 0, (size_t)NTOK*DS*sizeof(float), stream);

  ln_kernel<<<NTOK, 256, 0, stream>>>(x, norm_w, norm_b, xn_y);
  gemm_kernel<0><<<dim3(24,64), 256, 0, stream>>>(xn_y, nullptr, in_w, in_b, nullptr,
                                                  xssm, sgate, NTOK, 2*DM, DM);
  conv_silu_kernel<<<(NTOK*DM)/256, 256, 0, stream>>>(xssm, conv_w, conv_b, xconv);
  transpose_w<<<96, 256, 0, stream>>>(xp_w, wt);
  xproj_kernel<<<NTOK/8, 256, 0, stream>>>(xconv, wt, xp_b, BC);
  scan_kernel<<<96, 64, 0, stream>>>(xconv, BC, op_probs, A_log, D_param, gate_l,
                                     coll_t, xn_y, out1);
  gemm_kernel<1><<<dim3(12,64), 256, 0, stream>>>(xn_y, sgate, out_w, out_b, x,
                                                  out0, nullptr, NTOK, DM, DM);
}

// Round 2
// 940.446 us; speedup vs baseline: 1.6721x; 1.6721x over previous
//
#include <hip/hip_runtime.h>
#include <math.h>

#define BB 2
#define LL 2048
#define DM 768
#define DS 16
#define NTOK (BB*LL)

__device__ __forceinline__ float sigf(float x){ return 1.f/(1.f+__expf(-x)); }

// ---------------- LayerNorm: one block per token ----------------
__global__ __launch_bounds__(256) void ln_kernel(const float* __restrict__ x,
                                                 const float* __restrict__ w,
                                                 const float* __restrict__ b,
                                                 float* __restrict__ xn){
  __shared__ float red[8];
  int tok = blockIdx.x, tid = threadIdx.x;
  const float* xr = x + (size_t)tok*DM;
  float a0 = xr[tid], a1 = xr[tid+256], a2 = xr[tid+512];
  float s = a0+a1+a2;
  float q = a0*a0 + a1*a1 + a2*a2;
  #pragma unroll
  for (int o=32;o>=1;o>>=1){ s += __shfl_xor(s,o); q += __shfl_xor(q,o); }
  int wid = tid>>6;
  if ((tid&63)==0){ red[wid]=s; red[4+wid]=q; }
  __syncthreads();
  if (tid==0){
    float S = red[0]+red[1]+red[2]+red[3];
    float Q = red[4]+red[5]+red[6]+red[7];
    float mu = S*(1.f/768.f);
    float var = Q*(1.f/768.f) - mu*mu;
    red[0]=mu; red[1]=rsqrtf(var+1e-5f);
  }
  __syncthreads();
  float mu = red[0], r = red[1];
  float* o = xn + (size_t)tok*DM;
  o[tid]     = (a0-mu)*r*w[tid]     + b[tid];
  o[tid+256] = (a1-mu)*r*w[tid+256] + b[tid+256];
  o[tid+512] = (a2-mu)*r*w[tid+512] + b[tid+512];
}

// ---------------- Tiled fp32 GEMM: C[M,N] = A[M,K] @ W[N,K]^T + bias ----------------
template<int MODE>
__global__ __launch_bounds__(256) void gemm_kernel(const float* __restrict__ A,
                                                   const float* __restrict__ A2,
                                                   const float* __restrict__ W,
                                                   const float* __restrict__ bias,
                                                   const float* __restrict__ resid,
                                                   float* __restrict__ out0,
                                                   float* __restrict__ out1,
                                                   int M, int N, int K){
  __shared__ float As[64][17];
  __shared__ float Bs[64][17];
  int tid = threadIdx.x;
  int m0 = blockIdx.y*64, n0 = blockIdx.x*64;
  int lr = tid>>2;         // 0..63
  int lk = (tid&3)*4;      // 0,4,8,12
  int ty = tid>>4, tx = tid&15;
  float acc[4][4] = {};
  for (int k0=0; k0<K; k0+=16){
    float4 a4 = *(const float4*)(A + (size_t)(m0+lr)*K + k0 + lk);
    if (MODE==1){
      float4 g4 = *(const float4*)(A2 + (size_t)(m0+lr)*K + k0 + lk);
      a4.x*=g4.x; a4.y*=g4.y; a4.z*=g4.z; a4.w*=g4.w;
    }
    float4 b4 = *(const float4*)(W + (size_t)(n0+lr)*K + k0 + lk);
    As[lr][lk]=a4.x; As[lr][lk+1]=a4.y; As[lr][lk+2]=a4.z; As[lr][lk+3]=a4.w;
    Bs[lr][lk]=b4.x; Bs[lr][lk+1]=b4.y; Bs[lr][lk+2]=b4.z; Bs[lr][lk+3]=b4.w;
    __syncthreads();
    #pragma unroll
    for (int kk=0; kk<16; kk++){
      float a[4], bb[4];
      #pragma unroll
      for (int i=0;i<4;i++) a[i]  = As[ty*4+i][kk];
      #pragma unroll
      for (int j=0;j<4;j++) bb[j] = Bs[tx*4+j][kk];
      #pragma unroll
      for (int i=0;i<4;i++)
        #pragma unroll
        for (int j=0;j<4;j++)
          acc[i][j] = fmaf(a[i], bb[j], acc[i][j]);
    }
    __syncthreads();
  }
  #pragma unroll
  for (int i=0;i<4;i++){
    int row = m0 + ty*4 + i;
    #pragma unroll
    for (int j=0;j<4;j++){
      int col = n0 + tx*4 + j;
      float v = acc[i][j] + bias[col];
      if (MODE==0){
        if (col < DM) out0[(size_t)row*DM + col] = v;
        else          out1[(size_t)row*DM + (col-DM)] = v/(1.f+__expf(-v));
      } else {
        out0[(size_t)row*DM + col] = v + resid[(size_t)row*DM + col];
      }
    }
  }
}

// ---------------- causal depthwise conv (k=4) + SiLU ----------------
__global__ __launch_bounds__(256) void conv_silu_kernel(const float* __restrict__ xs,
                                                        const float* __restrict__ cw,
                                                        const float* __restrict__ cb,
                                                        float* __restrict__ xc){
  int idx = blockIdx.x*256 + threadIdx.x;
  if (idx >= NTOK*DM) return;
  int d = idx % DM;
  int l = (idx / DM) % LL;
  float acc = cb[d] + cw[d*4+3]*xs[idx];
  if (l>=1) acc = fmaf(cw[d*4+2], xs[idx-DM],   acc);
  if (l>=2) acc = fmaf(cw[d*4+1], xs[idx-2*DM], acc);
  if (l>=3) acc = fmaf(cw[d*4+0], xs[idx-3*DM], acc);
  xc[idx] = acc/(1.f+__expf(-acc));
}

// ---------------- transpose x_proj_w [32,768] -> [768,32] ----------------
__global__ __launch_bounds__(256) void transpose_w(const float* __restrict__ w,
                                                   float* __restrict__ wt){
  int idx = blockIdx.x*256 + threadIdx.x;
  if (idx >= 32*768) return;
  int n = idx/768, k = idx%768;
  wt[k*32+n] = w[idx];
}

// ---------------- x_proj: BC[NTOK,32] = xc @ wt + b ----------------
__global__ __launch_bounds__(256) void xproj_kernel(const float* __restrict__ xc,
                                                    const float* __restrict__ wt,
                                                    const float* __restrict__ bias,
                                                    float* __restrict__ BC){
  int tid = threadIdx.x;
  int n = tid & 31, tloc = tid >> 5;
  int m = blockIdx.x*8 + tloc;
  const float* xr = xc + (size_t)m*DM;
  float a0=0,a1=0,a2=0,a3=0;
  #pragma unroll 4
  for (int k=0;k<DM;k+=4){
    a0 = fmaf(xr[k],   wt[(k)*32+n],   a0);
    a1 = fmaf(xr[k+1], wt[(k+1)*32+n], a1);
    a2 = fmaf(xr[k+2], wt[(k+2)*32+n], a2);
    a3 = fmaf(xr[k+3], wt[(k+3)*32+n], a3);
  }
  BC[(size_t)m*32+n] = (a0+a1)+(a2+a3) + bias[n];
}

// ---------------- sequential gated scan, LDS double-buffered ----------------
// 384 blocks x 64 threads. block -> (b, 4-channel chunk). thread -> (channel c = lane&3, state s = lane>>2)
#define TILE 64
#define NT (LL/TILE)
__global__ __launch_bounds__(64) void scan_kernel(const float* __restrict__ xconv,
                                                  const float* __restrict__ BC,
                                                  const float* __restrict__ opp,
                                                  const float* __restrict__ A_log,
                                                  const float* __restrict__ Dp_,
                                                  const float* __restrict__ gl,
                                                  const float* __restrict__ ctgt,
                                                  float* __restrict__ y,
                                                  float* __restrict__ states){
  __shared__ float4 xc_s[2][TILE];        // [buf][t] -> 4 d-values
  __shared__ float2 bc_s[2][TILE][16];    // [buf][t][slot] -> (B,C), slot = s ^ (t&15)
  __shared__ float4 op_s[2][TILE];        // [buf][t] -> (iw, pcs, cw, zw)

  int bid = blockIdx.x;
  int b = bid / 192, chunk = bid % 192;
  int lane = threadIdx.x;
  int c = lane & 3, s = lane >> 2;
  int d = chunk*4 + c;

  float A_ = expf(-expf(A_log[d*DS + s]));
  float ct = ctgt[s];
  float Dp = Dp_[d];
  float gs2 = sigf(gl[2]), gs4 = sigf(gl[4]), gs5 = sigf(gl[5]);
  const size_t base = (size_t)b * LL;

  // staging registers (one token row per lane)
  float4 xr; float4 br[8]; float4 opv;

  auto LOADT = [&](int t0){
    size_t tok = base + t0 + lane;
    xr = *(const float4*)(xconv + tok*DM + chunk*4);
    const float4* bp = (const float4*)(BC + tok*32);
    #pragma unroll
    for (int j=0;j<8;j++) br[j] = bp[j];
    const float* op = opp + tok*6;
    opv = make_float4(op[2]*gs2, op[3], op[4]*gs4, op[5]*gs5);
  };
  auto WRITET = [&](int buf){
    xc_s[buf][lane] = xr;
    op_s[buf][lane] = opv;
    const float* bf = (const float*)br;   // bf[0..15]=B, bf[16..31]=C
    #pragma unroll
    for (int ss=0; ss<16; ss++)
      bc_s[buf][lane][ss ^ (lane & 15)] = make_float2(bf[ss], bf[16+ss]);
  };

  float h = 0.f, ck = 0.f;
  LOADT(0);
  WRITET(0);
  __syncthreads();

  for (int tile=0; tile<NT; ++tile){
    int cur = tile & 1;
    if (tile+1 < NT) LOADT((tile+1)*TILE);   // issue next tile's global loads early
    size_t tokbase = base + (size_t)tile*TILE;
    #pragma unroll 4
    for (int tl=0; tl<TILE; ++tl){
      const float* xrow = (const float*)&xc_s[cur][tl];
      float xc = xrow[c];
      float2 bcv = bc_s[cur][tl][s ^ (tl & 15)];
      float4 o = op_s[cur][tl];
      float hold = h;
      float hn = fmaf(A_, hold, xc*bcv.x);
      ck = fmaf(o.y, hold - ck, ck);
      hn = fmaf(o.x, hold - hn, hn);
      hn = fmaf(o.z, ck   - hn, hn);
      hn = fmaf(o.w, ct   - hn, hn);
      h = hn;
      float yp = bcv.y * hn;
      yp += __shfl_xor(yp, 4);
      yp += __shfl_xor(yp, 8);
      yp += __shfl_xor(yp, 16);
      yp += __shfl_xor(yp, 32);
      if (lane < 4) y[(tokbase+tl)*DM + chunk*4 + lane] = fmaf(Dp, xc, yp);
      float z = hn + __shfl_xor(hn, 1);
      z += __shfl_xor(z, 2);
      if (c == 0) atomicAdd(states + (tokbase+tl)*DS + s, z*(1.f/768.f));
    }
    if (tile+1 < NT) WRITET(1-cur);          // write-late: vmcnt hidden under compute
    __syncthreads();
  }
}

extern "C" void kernel_launch(void* const* d_in, const int* in_sizes, int n_in,
                              void* d_out, int out_size, void* d_ws, size_t ws_size,
                              hipStream_t stream){
  const float* x        = (const float*)d_in[0];
  const float* op_probs = (const float*)d_in[1];
  const float* norm_w   = (const float*)d_in[2];
  const float* norm_b   = (const float*)d_in[3];
  const float* in_w     = (const float*)d_in[4];
  const float* in_b     = (const float*)d_in[5];
  const float* conv_w   = (const float*)d_in[6];
  const float* conv_b   = (const float*)d_in[7];
  const float* xp_w     = (const float*)d_in[8];
  const float* xp_b     = (const float*)d_in[9];
  const float* out_w    = (const float*)d_in[10];
  const float* out_b    = (const float*)d_in[11];
  const float* A_log    = (const float*)d_in[12];
  const float* D_param  = (const float*)d_in[13];
  const float* gate_l   = (const float*)d_in[14];
  const float* coll_t   = (const float*)d_in[15];

  float* out0 = (float*)d_out;
  float* out1 = out0 + (size_t)NTOK*DM;

  float* ws    = (float*)d_ws;
  const size_t SZ = (size_t)NTOK*DM;       // 3145728
  float* xn_y  = ws;            // xn, later reused for scan y
  float* xssm  = ws + SZ;
  float* sgate = ws + 2*SZ;
  float* xconv = ws + 3*SZ;
  float* BC    = ws + 4*SZ;     // NTOK*32
  float* wt    = BC + (size_t)NTOK*32;  // 768*32

  hipMemsetAsync(out1, 0, (size_t)NTOK*DS*sizeof(float), stream);

  ln_kernel<<<NTOK, 256, 0, stream>>>(x, norm_w, norm_b, xn_y);
  gemm_kernel<0><<<dim3(24,64), 256, 0, stream>>>(xn_y, nullptr, in_w, in_b, nullptr,
                                                  xssm, sgate, NTOK, 2*DM, DM);
  conv_silu_kernel<<<(NTOK*DM)/256, 256, 0, stream>>>(xssm, conv_w, conv_b, xconv);
  transpose_w<<<96, 256, 0, stream>>>(xp_w, wt);
  xproj_kernel<<<NTOK/8, 256, 0, stream>>>(xconv, wt, xp_b, BC);
  scan_kernel<<<384, 64, 0, stream>>>(xconv, BC, op_probs, A_log, D_param, gate_l,
                                      coll_t, xn_y, out1);
  gemm_kernel<1><<<dim3(12,64), 256, 0, stream>>>(xn_y, sgate, out_w, out_b, x,
                                                  out0, nullptr, NTOK, DM, DM);
}

// Round 3
// 532.219 us; speedup vs baseline: 2.9546x; 1.7670x over previous
//
#include <hip/hip_runtime.h>
#include <math.h>

#define BB 2
#define LL 2048
#define DM 768
#define DS 16
#define NTOK (BB*LL)
#define CH 128
#define NCH (LL/CH)
#define NDS (DM*DS)          // 12288 (d,s) pairs
#define DBLK (NDS/256)       // 48 blocks of 256 (d,s) pairs

__device__ __forceinline__ float sigf(float x){ return 1.f/(1.f+__expf(-x)); }

// ---------------- LayerNorm: one block per token ----------------
__global__ __launch_bounds__(256) void ln_kernel(const float* __restrict__ x,
                                                 const float* __restrict__ w,
                                                 const float* __restrict__ b,
                                                 float* __restrict__ xn){
  __shared__ float red[8];
  int tok = blockIdx.x, tid = threadIdx.x;
  const float* xr = x + (size_t)tok*DM;
  float a0 = xr[tid], a1 = xr[tid+256], a2 = xr[tid+512];
  float s = a0+a1+a2;
  float q = a0*a0 + a1*a1 + a2*a2;
  #pragma unroll
  for (int o=32;o>=1;o>>=1){ s += __shfl_xor(s,o); q += __shfl_xor(q,o); }
  int wid = tid>>6;
  if ((tid&63)==0){ red[wid]=s; red[4+wid]=q; }
  __syncthreads();
  if (tid==0){
    float S = red[0]+red[1]+red[2]+red[3];
    float Q = red[4]+red[5]+red[6]+red[7];
    float mu = S*(1.f/768.f);
    float var = Q*(1.f/768.f) - mu*mu;
    red[0]=mu; red[1]=rsqrtf(var+1e-5f);
  }
  __syncthreads();
  float mu = red[0], r = red[1];
  float* o = xn + (size_t)tok*DM;
  o[tid]     = (a0-mu)*r*w[tid]     + b[tid];
  o[tid+256] = (a1-mu)*r*w[tid+256] + b[tid+256];
  o[tid+512] = (a2-mu)*r*w[tid+512] + b[tid+512];
}

// ---------------- Tiled fp32 GEMM: C[M,N] = A[M,K] @ W[N,K]^T + bias ----------------
template<int MODE>
__global__ __launch_bounds__(256) void gemm_kernel(const float* __restrict__ A,
                                                   const float* __restrict__ A2,
                                                   const float* __restrict__ W,
                                                   const float* __restrict__ bias,
                                                   const float* __restrict__ resid,
                                                   float* __restrict__ out0,
                                                   float* __restrict__ out1,
                                                   int M, int N, int K){
  __shared__ float As[64][17];
  __shared__ float Bs[64][17];
  int tid = threadIdx.x;
  int m0 = blockIdx.y*64, n0 = blockIdx.x*64;
  int lr = tid>>2;
  int lk = (tid&3)*4;
  int ty = tid>>4, tx = tid&15;
  float acc[4][4] = {};
  for (int k0=0; k0<K; k0+=16){
    float4 a4 = *(const float4*)(A + (size_t)(m0+lr)*K + k0 + lk);
    if (MODE==1){
      float4 g4 = *(const float4*)(A2 + (size_t)(m0+lr)*K + k0 + lk);
      a4.x*=g4.x; a4.y*=g4.y; a4.z*=g4.z; a4.w*=g4.w;
    }
    float4 b4 = *(const float4*)(W + (size_t)(n0+lr)*K + k0 + lk);
    As[lr][lk]=a4.x; As[lr][lk+1]=a4.y; As[lr][lk+2]=a4.z; As[lr][lk+3]=a4.w;
    Bs[lr][lk]=b4.x; Bs[lr][lk+1]=b4.y; Bs[lr][lk+2]=b4.z; Bs[lr][lk+3]=b4.w;
    __syncthreads();
    #pragma unroll
    for (int kk=0; kk<16; kk++){
      float a[4], bb[4];
      #pragma unroll
      for (int i=0;i<4;i++) a[i]  = As[ty*4+i][kk];
      #pragma unroll
      for (int j=0;j<4;j++) bb[j] = Bs[tx*4+j][kk];
      #pragma unroll
      for (int i=0;i<4;i++)
        #pragma unroll
        for (int j=0;j<4;j++)
          acc[i][j] = fmaf(a[i], bb[j], acc[i][j]);
    }
    __syncthreads();
  }
  #pragma unroll
  for (int i=0;i<4;i++){
    int row = m0 + ty*4 + i;
    #pragma unroll
    for (int j=0;j<4;j++){
      int col = n0 + tx*4 + j;
      float v = acc[i][j] + bias[col];
      if (MODE==0){
        if (col < DM) out0[(size_t)row*DM + col] = v;
        else          out1[(size_t)row*DM + (col-DM)] = v/(1.f+__expf(-v));
      } else {
        out0[(size_t)row*DM + col] = v + resid[(size_t)row*DM + col];
      }
    }
  }
}

// ---------------- causal depthwise conv (k=4) + SiLU ----------------
__global__ __launch_bounds__(256) void conv_silu_kernel(const float* __restrict__ xs,
                                                        const float* __restrict__ cw,
                                                        const float* __restrict__ cb,
                                                        float* __restrict__ xc){
  int idx = blockIdx.x*256 + threadIdx.x;
  if (idx >= NTOK*DM) return;
  int d = idx % DM;
  int l = (idx / DM) % LL;
  float acc = cb[d] + cw[d*4+3]*xs[idx];
  if (l>=1) acc = fmaf(cw[d*4+2], xs[idx-DM],   acc);
  if (l>=2) acc = fmaf(cw[d*4+1], xs[idx-2*DM], acc);
  if (l>=3) acc = fmaf(cw[d*4+0], xs[idx-3*DM], acc);
  xc[idx] = acc/(1.f+__expf(-acc));
}

// ---------------- transpose x_proj_w [32,768] -> [768,32] ----------------
__global__ __launch_bounds__(256) void transpose_w(const float* __restrict__ w,
                                                   float* __restrict__ wt){
  int idx = blockIdx.x*256 + threadIdx.x;
  if (idx >= 32*768) return;
  int n = idx/768, k = idx%768;
  wt[k*32+n] = w[idx];
}

// ---------------- x_proj: BC[NTOK,32] = xc @ wt + b ----------------
__global__ __launch_bounds__(256) void xproj_kernel(const float* __restrict__ xc,
                                                    const float* __restrict__ wt,
                                                    const float* __restrict__ bias,
                                                    float* __restrict__ BC){
  int tid = threadIdx.x;
  int n = tid & 31, tloc = tid >> 5;
  int m = blockIdx.x*8 + tloc;
  const float* xr = xc + (size_t)m*DM;
  float a0=0,a1=0,a2=0,a3=0;
  #pragma unroll 4
  for (int k=0;k<DM;k+=4){
    a0 = fmaf(xr[k],   wt[(k)*32+n],   a0);
    a1 = fmaf(xr[k+1], wt[(k+1)*32+n], a1);
    a2 = fmaf(xr[k+2], wt[(k+2)*32+n], a2);
    a3 = fmaf(xr[k+3], wt[(k+3)*32+n], a3);
  }
  BC[(size_t)m*32+n] = (a0+a1)+(a2+a3) + bias[n];
}

// ---------------- scan phase 0: per-token scalar coefficients ----------------
// coef[tok*8 + {0:c1, 1:c2, 2:b, 3:p, 4:zw}]
__global__ __launch_bounds__(256) void coef_kernel(const float* __restrict__ opp,
                                                   const float* __restrict__ gl,
                                                   float* __restrict__ coef){
  int tok = blockIdx.x*256 + threadIdx.x;
  if (tok >= NTOK) return;
  float gs2 = sigf(gl[2]), gs4 = sigf(gl[4]), gs5 = sigf(gl[5]);
  const float* op = opp + (size_t)tok*6;
  float iw = op[2]*gs2, pcs = op[3], cw = op[4]*gs4, zw = op[5]*gs5;
  float omz = 1.f-zw, omc = 1.f-cw, omi = 1.f-iw;
  float c1 = omz*omc*omi;
  float c2 = omz*(omc*iw + cw*pcs);
  float bb = omz*cw*(1.f-pcs);
  float* cf = coef + (size_t)tok*8;
  cf[0]=c1; cf[1]=c2; cf[2]=bb; cf[3]=pcs; cf[4]=zw; cf[5]=0; cf[6]=0; cf[7]=0;
}

// ---------------- scan phase 1: compose per-chunk affine maps ----------------
// Step map on (h,ck): h' = a*h + b*ck + v0;  ck' = p*h + (1-p)*ck
// a = c1*A + c2,  v0 = c1*xc*B + zw*ct[s]
// MV layout SoA: MV[((b*NCH+ch)*6 + comp)*NDS + dsidx]
__global__ __launch_bounds__(256) void compose_kernel(const float* __restrict__ xconv,
                                                      const float* __restrict__ BC,
                                                      const float* __restrict__ coef,
                                                      const float* __restrict__ A_log,
                                                      const float* __restrict__ ctgt,
                                                      float* __restrict__ MV){
  int blk = blockIdx.x;
  int b = blk/(NCH*DBLK); int r = blk%(NCH*DBLK); int ch = r/DBLK; int dblk = r%DBLK;
  int tid = threadIdx.x;
  int dsidx = dblk*256 + tid;
  int d = dsidx>>4, s = dsidx&15;
  float A_ = expf(-expf(A_log[d*DS+s]));
  float zcS; { zcS = ctgt[s]; }
  float M00=1.f,M01=0.f,M10=0.f,M11=1.f,V0=0.f,V1=0.f;
  const size_t tbase = (size_t)b*LL + (size_t)ch*CH;
  #pragma unroll 4
  for (int t=0;t<CH;t++){
    size_t tok = tbase + t;
    float4 cA = *(const float4*)(coef + tok*8);       // c1,c2,b,p
    float zw  = coef[tok*8+4];
    float xc  = xconv[tok*DM + d];
    float B_  = BC[tok*32 + s];
    float a   = fmaf(cA.x, A_, cA.y);
    float v0  = fmaf(cA.x*xc, B_, zw*zcS);
    float p = cA.w, q = 1.f-p, bb = cA.z;
    float n00 = fmaf(a,M00, bb*M10), n01 = fmaf(a,M01, bb*M11);
    float n10 = fmaf(p,M00, q*M10),  n11 = fmaf(p,M01, q*M11);
    float nV0 = fmaf(a,V0, fmaf(bb,V1, v0));
    float nV1 = fmaf(p,V0, q*V1);
    M00=n00; M01=n01; M10=n10; M11=n11; V0=nV0; V1=nV1;
  }
  size_t o = (size_t)(b*NCH+ch)*6*NDS + dsidx;
  MV[o]=M00; MV[o+NDS]=M01; MV[o+2*NDS]=M10; MV[o+3*NDS]=M11; MV[o+4*NDS]=V0; MV[o+5*NDS]=V1;
}

// ---------------- scan phase 2: sequential scan over chunk maps ----------------
// bound layout: bound[(b*NCH+ch)*2*NDS + {0,NDS} + dsidx] = state ENTERING chunk
__global__ __launch_bounds__(256) void chunkscan_kernel(const float* __restrict__ MV,
                                                        float* __restrict__ bound){
  int idx = blockIdx.x*256 + threadIdx.x;   // b*NDS + dsidx
  int b = idx/NDS; int dsidx = idx%NDS;
  float h=0.f, ck=0.f;
  #pragma unroll
  for (int ch=0; ch<NCH; ch++){
    size_t bo = (size_t)(b*NCH+ch)*2*NDS + dsidx;
    bound[bo] = h; bound[bo+NDS] = ck;
    size_t o = (size_t)(b*NCH+ch)*6*NDS + dsidx;
    float m00=MV[o], m01=MV[o+NDS], m10=MV[o+2*NDS], m11=MV[o+3*NDS];
    float v0=MV[o+4*NDS], v1=MV[o+5*NDS];
    float hn = fmaf(m00,h, fmaf(m01,ck, v0));
    float cn = fmaf(m10,h, fmaf(m11,ck, v1));
    h=hn; ck=cn;
  }
}

// ---------------- scan phase 3: replay chunks, emit y and states ----------------
__global__ __launch_bounds__(256) void emit_kernel(const float* __restrict__ xconv,
                                                   const float* __restrict__ BC,
                                                   const float* __restrict__ coef,
                                                   const float* __restrict__ A_log,
                                                   const float* __restrict__ ctgt,
                                                   const float* __restrict__ Dp_,
                                                   const float* __restrict__ bound,
                                                   float* __restrict__ y,
                                                   float* __restrict__ states){
  __shared__ float sm[CH][DS];   // 8 KB state-sum accumulator
  int blk = blockIdx.x;
  int b = blk/(NCH*DBLK); int r = blk%(NCH*DBLK); int ch = r/DBLK; int dblk = r%DBLK;
  int tid = threadIdx.x;
  for (int i=tid;i<CH*DS;i+=256) ((float*)sm)[i]=0.f;
  int dsidx = dblk*256 + tid;
  int d = dsidx>>4, s = dsidx&15;
  float A_ = expf(-expf(A_log[d*DS+s]));
  float ctS = ctgt[s];
  float Dp = Dp_[d];
  size_t bo = (size_t)(b*NCH+ch)*2*NDS + dsidx;
  float h = bound[bo], ck = bound[bo+NDS];
  __syncthreads();
  const size_t tbase = (size_t)b*LL + (size_t)ch*CH;
  #pragma unroll 4
  for (int t=0;t<CH;t++){
    size_t tok = tbase + t;
    float4 cA = *(const float4*)(coef + tok*8);
    float zw  = coef[tok*8+4];
    float xc  = xconv[tok*DM + d];
    float B_  = BC[tok*32 + s];
    float C_  = BC[tok*32 + 16 + s];
    float a   = fmaf(cA.x, A_, cA.y);
    float v0  = fmaf(cA.x*xc, B_, zw*ctS);
    float hn  = fmaf(a,h, fmaf(cA.z,ck, v0));
    ck = fmaf(cA.w, h-ck, ck);
    h = hn;
    float yp = C_*h;
    yp += __shfl_xor(yp,1); yp += __shfl_xor(yp,2);
    yp += __shfl_xor(yp,4); yp += __shfl_xor(yp,8);
    if ((tid&15)==0) y[tok*DM + d] = fmaf(Dp, xc, yp);
    float z = h + __shfl_xor(h,16);
    z += __shfl_xor(z,32);
    if ((tid&63) < 16) atomicAdd(&sm[t][tid&15], z);
  }
  __syncthreads();
  for (int i=tid;i<CH*DS;i+=256){
    int t=i>>4, s2=i&15;
    atomicAdd(states + (tbase+t)*DS + s2, sm[t][s2]*(1.f/768.f));
  }
}

extern "C" void kernel_launch(void* const* d_in, const int* in_sizes, int n_in,
                              void* d_out, int out_size, void* d_ws, size_t ws_size,
                              hipStream_t stream){
  const float* x        = (const float*)d_in[0];
  const float* op_probs = (const float*)d_in[1];
  const float* norm_w   = (const float*)d_in[2];
  const float* norm_b   = (const float*)d_in[3];
  const float* in_w     = (const float*)d_in[4];
  const float* in_b     = (const float*)d_in[5];
  const float* conv_w   = (const float*)d_in[6];
  const float* conv_b   = (const float*)d_in[7];
  const float* xp_w     = (const float*)d_in[8];
  const float* xp_b     = (const float*)d_in[9];
  const float* out_w    = (const float*)d_in[10];
  const float* out_b    = (const float*)d_in[11];
  const float* A_log    = (const float*)d_in[12];
  const float* D_param  = (const float*)d_in[13];
  const float* gate_l   = (const float*)d_in[14];
  const float* coll_t   = (const float*)d_in[15];

  float* out0 = (float*)d_out;
  float* out1 = out0 + (size_t)NTOK*DM;

  float* ws    = (float*)d_ws;
  const size_t SZ = (size_t)NTOK*DM;       // 3145728 floats
  float* xn_y  = ws;                        // xn, later reused for scan y
  float* xssm  = ws + SZ;                   // gemm0 out; dead after conv -> reused as MV
  float* sgate = ws + 2*SZ;
  float* xconv = ws + 3*SZ;
  float* BC    = ws + 4*SZ;                 // NTOK*32 floats
  float* wt    = BC + (size_t)NTOK*32;      // 768*32
  float* coef  = wt + 24576;                // NTOK*8
  float* bound = coef + (size_t)NTOK*8;     // 2*NCH*2*NDS = 786432
  float* MV    = xssm;                      // 2*NCH*6*NDS = 2359296 < SZ

  hipMemsetAsync(out1, 0, (size_t)NTOK*DS*sizeof(float), stream);

  ln_kernel<<<NTOK, 256, 0, stream>>>(x, norm_w, norm_b, xn_y);
  gemm_kernel<0><<<dim3(24,64), 256, 0, stream>>>(xn_y, nullptr, in_w, in_b, nullptr,
                                                  xssm, sgate, NTOK, 2*DM, DM);
  conv_silu_kernel<<<(NTOK*DM)/256, 256, 0, stream>>>(xssm, conv_w, conv_b, xconv);
  transpose_w<<<96, 256, 0, stream>>>(xp_w, wt);
  xproj_kernel<<<NTOK/8, 256, 0, stream>>>(xconv, wt, xp_b, BC);
  coef_kernel<<<NTOK/256, 256, 0, stream>>>(op_probs, gate_l, coef);
  compose_kernel<<<BB*NCH*DBLK, 256, 0, stream>>>(xconv, BC, coef, A_log, coll_t, MV);
  chunkscan_kernel<<<BB*NDS/256, 256, 0, stream>>>(MV, bound);
  emit_kernel<<<BB*NCH*DBLK, 256, 0, stream>>>(xconv, BC, coef, A_log, coll_t, D_param,
                                               bound, xn_y, out1);
  gemm_kernel<1><<<dim3(12,64), 256, 0, stream>>>(xn_y, sgate, out_w, out_b, x,
                                                  out0, nullptr, NTOK, DM, DM);
}

// Round 4
// 279.441 us; speedup vs baseline: 5.6272x; 1.9046x over previous
//
#include <hip/hip_runtime.h>
#include <hip/hip_bf16.h>
#include <math.h>

#define BB 2
#define LL 2048
#define DM 768
#define DS 16
#define NTOK (BB*LL)
#define CH 128
#define NCH (LL/CH)
#define NDS (DM*DS)          // 12288 (d,s) pairs
#define DBLK (NDS/256)       // 48 blocks of 256 (d,s) pairs

typedef __attribute__((ext_vector_type(8))) short short8;
typedef __attribute__((ext_vector_type(4))) float f32x4;

__device__ __forceinline__ float sigf(float x){ return 1.f/(1.f+__expf(-x)); }

// ---------------- LayerNorm: one block per token, emits bf16 ----------------
__global__ __launch_bounds__(256) void ln_kernel(const float* __restrict__ x,
                                                 const float* __restrict__ w,
                                                 const float* __restrict__ b,
                                                 __hip_bfloat16* __restrict__ xn){
  __shared__ float red[8];
  int tok = blockIdx.x, tid = threadIdx.x;
  const float* xr = x + (size_t)tok*DM;
  float a0 = xr[tid], a1 = xr[tid+256], a2 = xr[tid+512];
  float s = a0+a1+a2;
  float q = a0*a0 + a1*a1 + a2*a2;
  #pragma unroll
  for (int o=32;o>=1;o>>=1){ s += __shfl_xor(s,o); q += __shfl_xor(q,o); }
  int wid = tid>>6;
  if ((tid&63)==0){ red[wid]=s; red[4+wid]=q; }
  __syncthreads();
  if (tid==0){
    float S = red[0]+red[1]+red[2]+red[3];
    float Q = red[4]+red[5]+red[6]+red[7];
    float mu = S*(1.f/768.f);
    float var = Q*(1.f/768.f) - mu*mu;
    red[0]=mu; red[1]=rsqrtf(var+1e-5f);
  }
  __syncthreads();
  float mu = red[0], r = red[1];
  __hip_bfloat16* o = xn + (size_t)tok*DM;
  o[tid]     = __float2bfloat16((a0-mu)*r*w[tid]     + b[tid]);
  o[tid+256] = __float2bfloat16((a1-mu)*r*w[tid+256] + b[tid+256]);
  o[tid+512] = __float2bfloat16((a2-mu)*r*w[tid+512] + b[tid+512]);
}

// ---------------- float -> bf16 convert ----------------
__global__ __launch_bounds__(256) void f2bf_kernel(const float* __restrict__ s,
                                                   __hip_bfloat16* __restrict__ d, int n){
  int i = (blockIdx.x*256 + threadIdx.x)*4;
  if (i >= n) return;
  float4 v = *(const float4*)(s+i);
  d[i]   = __float2bfloat16(v.x);
  d[i+1] = __float2bfloat16(v.y);
  d[i+2] = __float2bfloat16(v.z);
  d[i+3] = __float2bfloat16(v.w);
}

// ---------------- ygated = bf16(y * silu_gate) ----------------
__global__ __launch_bounds__(256) void ygate_kernel(const float* __restrict__ y,
                                                    const float* __restrict__ g,
                                                    __hip_bfloat16* __restrict__ d, int n){
  int i = (blockIdx.x*256 + threadIdx.x)*4;
  if (i >= n) return;
  float4 a = *(const float4*)(y+i);
  float4 b = *(const float4*)(g+i);
  d[i]   = __float2bfloat16(a.x*b.x);
  d[i+1] = __float2bfloat16(a.y*b.y);
  d[i+2] = __float2bfloat16(a.z*b.z);
  d[i+3] = __float2bfloat16(a.w*b.w);
}

// ---------------- bf16 MFMA GEMM: C[M,N] = A[M,K] @ W[N,K]^T + bias ----------------
// 128x128 tile, BK=32, 4 waves, 16x16x32 bf16 MFMA, global_load_lds staging with
// 2-way-max bank swizzle (granule q = g ^ ((row>>1)&3), swizzled on BOTH sides).
// MODE 0: col<DM -> out0 = v ; col>=DM -> out1 = silu(v)   (in_proj)
// MODE 1: out0 = v + resid                                  (out_proj)
template<int MODE>
__global__ __launch_bounds__(256) void gemm_mfma(const __hip_bfloat16* __restrict__ A,
                                                 const __hip_bfloat16* __restrict__ W,
                                                 const float* __restrict__ bias,
                                                 const float* __restrict__ resid,
                                                 float* __restrict__ out0,
                                                 float* __restrict__ out1,
                                                 int M, int N, int K){
  __shared__ __align__(16) short Atile[128*32];
  __shared__ __align__(16) short Btile[128*32];
  int tid = threadIdx.x;
  int m0 = blockIdx.y*128, n0 = blockIdx.x*128;

  // staging: 512 granules of 16B per tile; thread covers G0=tid, G1=tid+256.
  int G0 = tid, G1 = tid + 256;
  int ar0 = G0>>2, aq0 = ((G0&3) ^ ((ar0>>1)&3))*8;
  int ar1 = G1>>2, aq1 = ((G1&3) ^ ((ar1>>1)&3))*8;
  const __hip_bfloat16* a0p = A + (size_t)(m0+ar0)*K + aq0;
  const __hip_bfloat16* a1p = A + (size_t)(m0+ar1)*K + aq1;
  const __hip_bfloat16* b0p = W + (size_t)(n0+ar0)*K + aq0;
  const __hip_bfloat16* b1p = W + (size_t)(n0+ar1)*K + aq1;
  short* la0 = &Atile[G0*8]; short* la1 = &Atile[G1*8];
  short* lb0 = &Btile[G0*8]; short* lb1 = &Btile[G1*8];

  int lane = tid & 63, wv = tid>>6;
  int lr = lane & 15, lq = lane>>4;
  int wr = wv>>1, wc = wv&1;
  int g8 = (lq ^ ((lr>>1)&3))*8;
  int aoff = (wr*64+lr)*32 + g8;
  int boff = (wc*64+lr)*32 + g8;

  f32x4 acc[4][4] = {};

  for (int k0=0; k0<K; k0+=32){
    __builtin_amdgcn_global_load_lds((const __attribute__((address_space(1))) void*)(a0p+k0),
                                     (__attribute__((address_space(3))) void*)la0, 16, 0, 0);
    __builtin_amdgcn_global_load_lds((const __attribute__((address_space(1))) void*)(a1p+k0),
                                     (__attribute__((address_space(3))) void*)la1, 16, 0, 0);
    __builtin_amdgcn_global_load_lds((const __attribute__((address_space(1))) void*)(b0p+k0),
                                     (__attribute__((address_space(3))) void*)lb0, 16, 0, 0);
    __builtin_amdgcn_global_load_lds((const __attribute__((address_space(1))) void*)(b1p+k0),
                                     (__attribute__((address_space(3))) void*)lb1, 16, 0, 0);
    __syncthreads();
    short8 af[4], bfr[4];
    #pragma unroll
    for (int i=0;i<4;i++) af[i]  = *(const short8*)&Atile[aoff + i*512];
    #pragma unroll
    for (int j=0;j<4;j++) bfr[j] = *(const short8*)&Btile[boff + j*512];
    #pragma unroll
    for (int i=0;i<4;i++)
      #pragma unroll
      for (int j=0;j<4;j++)
        acc[i][j] = __builtin_amdgcn_mfma_f32_16x16x32_bf16(af[i], bfr[j], acc[i][j], 0, 0, 0);
    __syncthreads();
  }

  // epilogue: C/D layout col=lane&15, row=(lane>>4)*4+reg  [measured m89/m91]
  int orow = m0 + wr*64 + lq*4;
  int ocol = n0 + wc*64 + lr;
  #pragma unroll
  for (int i=0;i<4;i++){
    #pragma unroll
    for (int j=0;j<4;j++){
      int col = ocol + j*16;
      float bv = bias[col];
      #pragma unroll
      for (int r=0;r<4;r++){
        int row = orow + i*16 + r;
        float v = acc[i][j][r] + bv;
        if (MODE==0){
          if (col < DM) out0[(size_t)row*DM + col] = v;
          else          out1[(size_t)row*DM + (col-DM)] = v/(1.f+__expf(-v));
        } else {
          out0[(size_t)row*DM + col] = v + resid[(size_t)row*DM + col];
        }
      }
    }
  }
}

// ---------------- causal depthwise conv (k=4) + SiLU ----------------
__global__ __launch_bounds__(256) void conv_silu_kernel(const float* __restrict__ xs,
                                                        const float* __restrict__ cw,
                                                        const float* __restrict__ cb,
                                                        float* __restrict__ xc){
  int idx = blockIdx.x*256 + threadIdx.x;
  if (idx >= NTOK*DM) return;
  int d = idx % DM;
  int l = (idx / DM) % LL;
  float acc = cb[d] + cw[d*4+3]*xs[idx];
  if (l>=1) acc = fmaf(cw[d*4+2], xs[idx-DM],   acc);
  if (l>=2) acc = fmaf(cw[d*4+1], xs[idx-2*DM], acc);
  if (l>=3) acc = fmaf(cw[d*4+0], xs[idx-3*DM], acc);
  xc[idx] = acc/(1.f+__expf(-acc));
}

// ---------------- transpose x_proj_w [32,768] -> [768,32] ----------------
__global__ __launch_bounds__(256) void transpose_w(const float* __restrict__ w,
                                                   float* __restrict__ wt){
  int idx = blockIdx.x*256 + threadIdx.x;
  if (idx >= 32*768) return;
  int n = idx/768, k = idx%768;
  wt[k*32+n] = w[idx];
}

// ---------------- x_proj: BC[NTOK,32] = xc @ wt + b ----------------
__global__ __launch_bounds__(256) void xproj_kernel(const float* __restrict__ xc,
                                                    const float* __restrict__ wt,
                                                    const float* __restrict__ bias,
                                                    float* __restrict__ BC){
  int tid = threadIdx.x;
  int n = tid & 31, tloc = tid >> 5;
  int m = blockIdx.x*8 + tloc;
  const float* xr = xc + (size_t)m*DM;
  float a0=0,a1=0,a2=0,a3=0;
  #pragma unroll 4
  for (int k=0;k<DM;k+=4){
    a0 = fmaf(xr[k],   wt[(k)*32+n],   a0);
    a1 = fmaf(xr[k+1], wt[(k+1)*32+n], a1);
    a2 = fmaf(xr[k+2], wt[(k+2)*32+n], a2);
    a3 = fmaf(xr[k+3], wt[(k+3)*32+n], a3);
  }
  BC[(size_t)m*32+n] = (a0+a1)+(a2+a3) + bias[n];
}

// ---------------- scan phase 0: per-token scalar coefficients ----------------
__global__ __launch_bounds__(256) void coef_kernel(const float* __restrict__ opp,
                                                   const float* __restrict__ gl,
                                                   float* __restrict__ coef){
  int tok = blockIdx.x*256 + threadIdx.x;
  if (tok >= NTOK) return;
  float gs2 = sigf(gl[2]), gs4 = sigf(gl[4]), gs5 = sigf(gl[5]);
  const float* op = opp + (size_t)tok*6;
  float iw = op[2]*gs2, pcs = op[3], cw = op[4]*gs4, zw = op[5]*gs5;
  float omz = 1.f-zw, omc = 1.f-cw, omi = 1.f-iw;
  float c1 = omz*omc*omi;
  float c2 = omz*(omc*iw + cw*pcs);
  float bb = omz*cw*(1.f-pcs);
  float* cf = coef + (size_t)tok*8;
  cf[0]=c1; cf[1]=c2; cf[2]=bb; cf[3]=pcs; cf[4]=zw; cf[5]=0; cf[6]=0; cf[7]=0;
}

// ---------------- scan phase 1: compose per-chunk affine maps ----------------
__global__ __launch_bounds__(256) void compose_kernel(const float* __restrict__ xconv,
                                                      const float* __restrict__ BC,
                                                      const float* __restrict__ coef,
                                                      const float* __restrict__ A_log,
                                                      const float* __restrict__ ctgt,
                                                      float* __restrict__ MV){
  int blk = blockIdx.x;
  int b = blk/(NCH*DBLK); int r = blk%(NCH*DBLK); int ch = r/DBLK; int dblk = r%DBLK;
  int tid = threadIdx.x;
  int dsidx = dblk*256 + tid;
  int d = dsidx>>4, s = dsidx&15;
  float A_ = expf(-expf(A_log[d*DS+s]));
  float zcS = ctgt[s];
  float M00=1.f,M01=0.f,M10=0.f,M11=1.f,V0=0.f,V1=0.f;
  const size_t tbase = (size_t)b*LL + (size_t)ch*CH;
  #pragma unroll 4
  for (int t=0;t<CH;t++){
    size_t tok = tbase + t;
    float4 cA = *(const float4*)(coef + tok*8);
    float zw  = coef[tok*8+4];
    float xc  = xconv[tok*DM + d];
    float B_  = BC[tok*32 + s];
    float a   = fmaf(cA.x, A_, cA.y);
    float v0  = fmaf(cA.x*xc, B_, zw*zcS);
    float p = cA.w, q = 1.f-p, bb = cA.z;
    float n00 = fmaf(a,M00, bb*M10), n01 = fmaf(a,M01, bb*M11);
    float n10 = fmaf(p,M00, q*M10),  n11 = fmaf(p,M01, q*M11);
    float nV0 = fmaf(a,V0, fmaf(bb,V1, v0));
    float nV1 = fmaf(p,V0, q*V1);
    M00=n00; M01=n01; M10=n10; M11=n11; V0=nV0; V1=nV1;
  }
  size_t o = (size_t)(b*NCH+ch)*6*NDS + dsidx;
  MV[o]=M00; MV[o+NDS]=M01; MV[o+2*NDS]=M10; MV[o+3*NDS]=M11; MV[o+4*NDS]=V0; MV[o+5*NDS]=V1;
}

// ---------------- scan phase 2: sequential scan over chunk maps ----------------
__global__ __launch_bounds__(256) void chunkscan_kernel(const float* __restrict__ MV,
                                                        float* __restrict__ bound){
  int idx = blockIdx.x*256 + threadIdx.x;
  int b = idx/NDS; int dsidx = idx%NDS;
  float h=0.f, ck=0.f;
  #pragma unroll
  for (int ch=0; ch<NCH; ch++){
    size_t bo = (size_t)(b*NCH+ch)*2*NDS + dsidx;
    bound[bo] = h; bound[bo+NDS] = ck;
    size_t o = (size_t)(b*NCH+ch)*6*NDS + dsidx;
    float m00=MV[o], m01=MV[o+NDS], m10=MV[o+2*NDS], m11=MV[o+3*NDS];
    float v0=MV[o+4*NDS], v1=MV[o+5*NDS];
    float hn = fmaf(m00,h, fmaf(m01,ck, v0));
    float cn = fmaf(m10,h, fmaf(m11,ck, v1));
    h=hn; ck=cn;
  }
}

// ---------------- scan phase 3: replay chunks, emit y and states ----------------
__global__ __launch_bounds__(256) void emit_kernel(const float* __restrict__ xconv,
                                                   const float* __restrict__ BC,
                                                   const float* __restrict__ coef,
                                                   const float* __restrict__ A_log,
                                                   const float* __restrict__ ctgt,
                                                   const float* __restrict__ Dp_,
                                                   const float* __restrict__ bound,
                                                   float* __restrict__ y,
                                                   float* __restrict__ states){
  __shared__ float sm[CH][DS];
  int blk = blockIdx.x;
  int b = blk/(NCH*DBLK); int r = blk%(NCH*DBLK); int ch = r/DBLK; int dblk = r%DBLK;
  int tid = threadIdx.x;
  for (int i=tid;i<CH*DS;i+=256) ((float*)sm)[i]=0.f;
  int dsidx = dblk*256 + tid;
  int d = dsidx>>4, s = dsidx&15;
  float A_ = expf(-expf(A_log[d*DS+s]));
  float ctS = ctgt[s];
  float Dp = Dp_[d];
  size_t bo = (size_t)(b*NCH+ch)*2*NDS + dsidx;
  float h = bound[bo], ck = bound[bo+NDS];
  __syncthreads();
  const size_t tbase = (size_t)b*LL + (size_t)ch*CH;
  #pragma unroll 4
  for (int t=0;t<CH;t++){
    size_t tok = tbase + t;
    float4 cA = *(const float4*)(coef + tok*8);
    float zw  = coef[tok*8+4];
    float xc  = xconv[tok*DM + d];
    float B_  = BC[tok*32 + s];
    float C_  = BC[tok*32 + 16 + s];
    float a   = fmaf(cA.x, A_, cA.y);
    float v0  = fmaf(cA.x*xc, B_, zw*ctS);
    float hn  = fmaf(a,h, fmaf(cA.z,ck, v0));
    ck = fmaf(cA.w, h-ck, ck);
    h = hn;
    float yp = C_*h;
    yp += __shfl_xor(yp,1); yp += __shfl_xor(yp,2);
    yp += __shfl_xor(yp,4); yp += __shfl_xor(yp,8);
    if ((tid&15)==0) y[tok*DM + d] = fmaf(Dp, xc, yp);
    float z = h + __shfl_xor(h,16);
    z += __shfl_xor(z,32);
    if ((tid&63) < 16) atomicAdd(&sm[t][tid&15], z);
  }
  __syncthreads();
  for (int i=tid;i<CH*DS;i+=256){
    int t=i>>4, s2=i&15;
    atomicAdd(states + (tbase+t)*DS + s2, sm[t][s2]*(1.f/768.f));
  }
}

extern "C" void kernel_launch(void* const* d_in, const int* in_sizes, int n_in,
                              void* d_out, int out_size, void* d_ws, size_t ws_size,
                              hipStream_t stream){
  const float* x        = (const float*)d_in[0];
  const float* op_probs = (const float*)d_in[1];
  const float* norm_w   = (const float*)d_in[2];
  const float* norm_b   = (const float*)d_in[3];
  const float* in_w     = (const float*)d_in[4];
  const float* in_b     = (const float*)d_in[5];
  const float* conv_w   = (const float*)d_in[6];
  const float* conv_b   = (const float*)d_in[7];
  const float* xp_w     = (const float*)d_in[8];
  const float* xp_b     = (const float*)d_in[9];
  const float* out_w    = (const float*)d_in[10];
  const float* out_b    = (const float*)d_in[11];
  const float* A_log    = (const float*)d_in[12];
  const float* D_param  = (const float*)d_in[13];
  const float* gate_l   = (const float*)d_in[14];
  const float* coll_t   = (const float*)d_in[15];

  float* out0 = (float*)d_out;
  float* out1 = out0 + (size_t)NTOK*DM;

  float* ws    = (float*)d_ws;
  const size_t SZ = (size_t)NTOK*DM;         // 3145728 floats
  float* xssm  = ws;                         // gemm0 out0; then MV; then y (aliased)
  float* sgate = ws + SZ;
  float* xconv = ws + 2*SZ;
  float* BC    = ws + 3*SZ;                  // NTOK*32
  float* wt    = BC + (size_t)NTOK*32;       // 768*32
  float* coef  = wt + 24576;                 // NTOK*8
  float* bound = coef + (size_t)NTOK*8;      // 786432
  float* endf  = bound + 786432;
  __hip_bfloat16* xn_bf = (__hip_bfloat16*)endf;  // NTOK*DM
  __hip_bfloat16* wi_bf = xn_bf + SZ;             // 1536*768
  __hip_bfloat16* wo_bf = wi_bf + (size_t)2*DM*DM;
  __hip_bfloat16* yg_bf = wo_bf + (size_t)DM*DM;  // NTOK*DM
  float* MV = xssm;                          // 2*16*6*12288 = 2359296 < SZ
  float* y  = xssm;                          // alias: MV dead after chunkscan

  hipMemsetAsync(out1, 0, (size_t)NTOK*DS*sizeof(float), stream);

  f2bf_kernel<<<(2*DM*DM)/1024, 256, 0, stream>>>(in_w, wi_bf, 2*DM*DM);
  f2bf_kernel<<<(DM*DM)/1024, 256, 0, stream>>>(out_w, wo_bf, DM*DM);
  ln_kernel<<<NTOK, 256, 0, stream>>>(x, norm_w, norm_b, xn_bf);
  gemm_mfma<0><<<dim3(12,32), 256, 0, stream>>>(xn_bf, wi_bf, in_b, nullptr,
                                                xssm, sgate, NTOK, 2*DM, DM);
  conv_silu_kernel<<<(NTOK*DM)/256, 256, 0, stream>>>(xssm, conv_w, conv_b, xconv);
  transpose_w<<<96, 256, 0, stream>>>(xp_w, wt);
  xproj_kernel<<<NTOK/8, 256, 0, stream>>>(xconv, wt, xp_b, BC);
  coef_kernel<<<NTOK/256, 256, 0, stream>>>(op_probs, gate_l, coef);
  compose_kernel<<<BB*NCH*DBLK, 256, 0, stream>>>(xconv, BC, coef, A_log, coll_t, MV);
  chunkscan_kernel<<<BB*NDS/256, 256, 0, stream>>>(MV, bound);
  emit_kernel<<<BB*NCH*DBLK, 256, 0, stream>>>(xconv, BC, coef, A_log, coll_t, D_param,
                                               bound, y, out1);
  ygate_kernel<<<(int)(SZ/1024), 256, 0, stream>>>(y, sgate, yg_bf, (int)SZ);
  gemm_mfma<1><<<dim3(6,32), 256, 0, stream>>>(yg_bf, wo_bf, out_b, x,
                                               out0, nullptr, NTOK, DM, DM);
}